// Round 17
// baseline (72.577 us; speedup 1.0000x reference)
//
#include <hip/hip_runtime.h>
#include <hip/hip_bf16.h>
#include <math.h>

#define H_  12
#define N_  1620
#define D_  64
#define C_  768
#define NS_ 20
#define V_  4
#define P_  400

#define TPP    64
#define PTILES 7    // ceil(400/64)
#define SPL    26   // spatial key splits of 64
#define NPANO  1008 // pano partial blocks: 336 tiles x 3 thirds
#define NPART  (NPANO + SPL * H_)   // 1320 total partial slots

typedef _Float16 f16x8 __attribute__((ext_vector_type(8)));
typedef float f32x4 __attribute__((ext_vector_type(4)));
typedef unsigned short ushort4v __attribute__((ext_vector_type(4)));
typedef unsigned int uint4v __attribute__((ext_vector_type(4)));

__device__ __forceinline__ unsigned short f16bits(float v) {
    return __builtin_bit_cast(unsigned short, (_Float16)v);
}
__device__ __forceinline__ float f16val(unsigned short u) {
    return (float)__builtin_bit_cast(_Float16, u);
}
// bijective XCD-chunked swizzle (m204)
__device__ __forceinline__ int xcd_swz(int orig, int nwg) {
    int q = nwg >> 3, r = nwg & 7;
    int x = orig & 7, p = orig >> 3;
    return (x < r ? x * (q + 1) : r * (q + 1) + (x - r) * q) + p;
}
__device__ __forceinline__ void gload16(const void* g, void* l) {
    __builtin_amdgcn_global_load_lds((const __attribute__((address_space(1))) void*)g,
                                     (__attribute__((address_space(3))) void*)l, 16, 0, 0);
}

// ---------------------------------------------------------------------------
#define N4_X  ((N_ * C_) / 4)
#define N4_W  ((3 * C_ * C_) / 4)
#define N4_PW ((C_ * C_) / 4)

__global__ __launch_bounds__(256)
void cvt_all(const float* __restrict__ x, const float* __restrict__ w,
             const float* __restrict__ pw,
             unsigned short* __restrict__ xf, unsigned short* __restrict__ wf,
             unsigned short* __restrict__ pwf)
{
    int i = blockIdx.x * 256 + threadIdx.x;
    const float* src; unsigned short* dst; int idx;
    if (i < N4_X)                { src = x;  dst = xf;  idx = i; }
    else if (i < N4_X + N4_W)    { src = w;  dst = wf;  idx = i - N4_X; }
    else if (i < N4_X + N4_W + N4_PW) { src = pw; dst = pwf; idx = i - N4_X - N4_W; }
    else return;
    float4 v = ((const float4*)src)[idx];
    ushort4v o;
    o.x = f16bits(v.x); o.y = f16bits(v.y); o.z = f16bits(v.z); o.w = f16bits(v.w);
    ((ushort4v*)dst)[idx] = o;
}

// ---------------------------------------------------------------------------
// Single-fp16 MFMA NT GEMM. Tile 64x64, BK=64, 4 waves (2x2, each 32x32).
// 3-buffer, 2-deep prefetch with COUNTED vmcnt + raw s_barrier:
//   iter t: wait vmcnt(t's loads done); s_barrier; STAGE(t+2); COMPUTE(t).
// STAGE = 4 global_load_lds per wave, so in-flight at the wait is <=8 and
// vmcnt(4) leaves only t+1's loads pending. Stage(t+2) is safe after the
// barrier: all waves have finished COMPUTE(t-1), which used buffer (t+2)%3.
// ---------------------------------------------------------------------------
template<int MODE>
__global__ __launch_bounds__(256)
void gemm_f16(const unsigned short* __restrict__ A, const unsigned short* __restrict__ B,
              const float* __restrict__ bias, int M, int N,
              float* __restrict__ out0, float* __restrict__ out1, float* __restrict__ out2)
{
    __shared__ unsigned short Ash[3][64][64];
    __shared__ unsigned short Bsh[3][64][64];
    const int tid = threadIdx.x;
    const int lane = tid & 63;
    const int w = tid >> 6;
    const int c = lane & 15;
    const int g = lane >> 4;

    const int wg = xcd_swz(blockIdx.x, gridDim.x);
    const int tmc = (M + 63) >> 6;
    const int tm = (wg % tmc) * 64;
    const int tn = (wg / tmc) * 64;

    const int wm = (w >> 1) * 32;
    const int wn = (w & 1) * 32;

    f32x4 acc[2][2] = {};

    const int srow = lane >> 3;
    const int ksrc = (((lane & 7) ^ srow) << 3);
    int gmA = tm + w * 16 + srow;
    const int gnB = tn + w * 16 + srow;

    auto STAGE = [&](int buf, int k0) {
        #pragma unroll
        for (int t = 0; t < 2; ++t) {
            int gm = gmA + t * 8; if (gm > M - 1) gm = M - 1;
            gload16(A + (size_t)gm * 768 + k0 + ksrc, &Ash[buf][w * 16 + t * 8][0]);
            gload16(B + (size_t)(gnB + t * 8) * 768 + k0 + ksrc, &Bsh[buf][w * 16 + t * 8][0]);
        }
    };
    auto COMPUTE = [&](int buf) {
        #pragma unroll
        for (int ss = 0; ss < 2; ++ss) {
            f16x8 af[2], bf[2];
            #pragma unroll
            for (int i = 0; i < 2; ++i) {
                int ra = wm + i * 16 + c;
                af[i] = *(const f16x8*)&Ash[buf][ra][(ss * 32 + g * 8) ^ ((ra & 7) << 3)];
                int rb = wn + i * 16 + c;
                bf[i] = *(const f16x8*)&Bsh[buf][rb][(ss * 32 + g * 8) ^ ((rb & 7) << 3)];
            }
            #pragma unroll
            for (int mi = 0; mi < 2; ++mi)
                #pragma unroll
                for (int ni = 0; ni < 2; ++ni)
                    acc[mi][ni] = __builtin_amdgcn_mfma_f32_16x16x32_f16(af[mi], bf[ni], acc[mi][ni], 0, 0, 0);
        }
    };

    // prologue: 2 tiles in flight
    STAGE(0, 0);
    STAGE(1, 64);
    for (int t = 0; t < 12; ++t) {
        if (t < 11) asm volatile("s_waitcnt vmcnt(4)" ::: "memory");
        else        asm volatile("s_waitcnt vmcnt(0)" ::: "memory");
        __builtin_amdgcn_s_barrier();
        if (t + 2 < 12) STAGE((t + 2) % 3, (t + 2) * 64);
        COMPUTE(t % 3);
    }

    const int fq = g * 4;
    #pragma unroll
    for (int mi = 0; mi < 2; ++mi) {
        #pragma unroll
        for (int ni = 0; ni < 2; ++ni) {
            int n = tn + wn + ni * 16 + c;
            float bb = bias[n];
            #pragma unroll
            for (int r = 0; r < 4; ++r) {
                int m = tm + wm + mi * 16 + fq + r;
                if (m >= M) continue;
                float val = acc[mi][ni][r] + bb;
                if (MODE == 0) {
                    out0[(size_t)m * N + n] = val;
                } else {
                    int which = n / C_;
                    int rr = n - which * C_;
                    int h = rr >> 6, d = rr & 63;
                    float* dst = (which == 0) ? out0 : (which == 1) ? out1 : out2;
                    ((unsigned short*)dst)[((size_t)h * N_ + m) * D_ + d] = f16bits(val);
                }
            }
        }
    }
}

// ---------------------------------------------------------------------------
// Unified attention partials, single-fp16 MFMA flash, double-buffered chunks.
// LDS 40 KB, one __syncthreads per chunk. Spatial blocks predicate waves with
// no live rows (wr >= 20) off the compute path (they still stage + barrier).
// ---------------------------------------------------------------------------
__global__ __launch_bounds__(256)
void attn_fused(const unsigned short* __restrict__ qp, const unsigned short* __restrict__ kp,
                const unsigned short* __restrict__ vp,
                unsigned short* __restrict__ po, float* __restrict__ pm, float* __restrict__ pl)
{
    __shared__ unsigned short Kf[2][64][64];
    __shared__ unsigned short Vf[2][64][64];
    __shared__ unsigned short Pf[64][64];

    const int tid = threadIdx.x;
    const int lane = tid & 63;
    const int w = tid >> 6;
    const int wr = w * 16;
    const int c = lane & 15;
    const int g = lane >> 4;

    const bool is_pano = (blockIdx.x < NPANO);
    int h, vw = 0, p0 = 0, cv = 0, n0 = 0, ch_lo, ch_hi, slot;
    if (is_pano) {
        int wg = xcd_swz(blockIdx.x, NPANO);
        int third = wg % 3;
        int t = wg / 3;
        int pt = t % PTILES;
        int t2 = t / PTILES;
        vw = t2 & 3;
        h  = t2 >> 2;
        p0 = pt * TPP;
        cv = (vw + 1) & 3;
        ch_lo = third * 3;
        ch_hi = third * 3 + 3;
        slot = wg;
    } else {
        int id = blockIdx.x - NPANO;
        int sp = id % SPL;
        h = id / SPL;
        n0 = sp * 64;
        ch_lo = 0; ch_hi = 1;
        slot = NPANO + id;
    }
    const bool active = is_pano || (wr < NS_);   // wave-uniform

    auto keyrow = [&](int ch, int key) -> int {
        int n;
        if (!is_pano) {
            n = n0 + key; if (n > N_ - 1) n = N_ - 1;
        } else if (ch < 7) {
            int sj = ch * 64 + key;
            n = (sj < NS_) ? sj : (NS_ + vw * P_ + (sj - NS_));
            if (sj >= NS_ + P_) n = 0;
        } else {
            int pp = p0 + (ch - 7) * 64 + key;
            if (pp >= P_) pp -= P_;
            if (pp >= P_) pp -= P_;
            n = NS_ + cv * P_ + pp;
        }
        return n;
    };

    auto stage_k = [&](int buf, int ch) {
        #pragma unroll
        for (int t = 0; t < 2; ++t) {
            int key = wr + t * 8 + (lane >> 3);
            int n = keyrow(ch, key);
            int dsrc = ((lane & 7) ^ (key & 7)) << 3;
            gload16(kp + (((size_t)h * N_ + n) << 6) + dsrc, &Kf[buf][wr + t * 8][0]);
        }
    };
    auto vload = [&](ushort4v* rr, int ch) {
        int kg = (tid & 15) << 2;
        int dq = (tid >> 4) << 2;
        #pragma unroll
        for (int tt = 0; tt < 4; ++tt) {
            int n = keyrow(ch, kg + tt);
            rr[tt] = *(const ushort4v*)(vp + (((size_t)h * N_ + n) << 6) + dq);
        }
    };
    auto vwrite = [&](int buf, const ushort4v* rr) {
        int kg = (tid & 15) << 2;
        int dq = (tid >> 4) << 2;
        #pragma unroll
        for (int j = 0; j < 4; ++j) {
            int d = dq + j;
            ushort4v wv;
            wv.x = rr[0][j]; wv.y = rr[1][j]; wv.z = rr[2][j]; wv.w = rr[3][j];
            *(ushort4v*)&Vf[buf][d][kg ^ ((d & 7) << 3)] = wv;
        }
    };

    f16x8 qf[2];
    {
        int rowq;
        if (is_pano) { rowq = NS_ + vw * P_ + p0 + wr + c; if (rowq > N_ - 1) rowq = N_ - 1; }
        else         { rowq = wr + c; if (rowq > NS_ - 1) rowq = NS_ - 1; }
        const unsigned short* qrow = qp + (((size_t)h * N_ + rowq) << 6);
        qf[0] = *(const f16x8*)(qrow + g * 8);
        qf[1] = *(const f16x8*)(qrow + 32 + g * 8);
    }

    float m[4], l[4];
    f32x4 o[4] = {};
    #pragma unroll
    for (int r = 0; r < 4; ++r) { m[r] = -INFINITY; l[r] = 0.f; }

    ushort4v vr[4];
    stage_k(0, ch_lo);
    vload(vr, ch_lo);
    vwrite(0, vr);
    __syncthreads();

    int buf = 0;
    for (int ch = ch_lo; ch < ch_hi; ++ch) {
        const bool pre = (ch + 1 < ch_hi);
        if (pre) {
            stage_k(buf ^ 1, ch + 1);
            vload(vr, ch + 1);
        }

        if (active) {
            f32x4 s[4] = {};
            #pragma unroll
            for (int ss = 0; ss < 2; ++ss) {
                #pragma unroll
                for (int nf = 0; nf < 4; ++nf) {
                    int key = nf * 16 + c;
                    int dx = (ss * 32 + g * 8) ^ ((key & 7) << 3);
                    f16x8 kf = *(const f16x8*)&Kf[buf][key][dx];
                    s[nf] = __builtin_amdgcn_mfma_f32_16x16x32_f16(qf[ss], kf, s[nf], 0, 0, 0);
                }
            }

            #pragma unroll
            for (int nf = 0; nf < 4; ++nf) {
                int col = nf * 16 + c;
                #pragma unroll
                for (int r = 0; r < 4; ++r) {
                    int rowl = wr + g * 4 + r;
                    bool valid;
                    if (!is_pano) {
                        valid = (n0 + col) < N_;
                    } else if (ch < 7) {
                        valid = (ch * 64 + col) < (NS_ + P_);
                    } else {
                        int i = (ch - 7) * 64 + col;
                        valid = (i < 127) && ((unsigned)(i - rowl) < 64u);
                    }
                    s[nf][r] = valid ? s[nf][r] * 0.125f : -INFINITY;
                }
            }

            float fct[4];
            #pragma unroll
            for (int r = 0; r < 4; ++r) {
                float cm = fmaxf(fmaxf(s[0][r], s[1][r]), fmaxf(s[2][r], s[3][r]));
                cm = fmaxf(cm, __shfl_xor(cm, 1, 64));
                cm = fmaxf(cm, __shfl_xor(cm, 2, 64));
                cm = fmaxf(cm, __shfl_xor(cm, 4, 64));
                cm = fmaxf(cm, __shfl_xor(cm, 8, 64));
                float nm = fmaxf(m[r], cm);
                fct[r] = __expf(m[r] - nm);
                m[r] = nm;
            }

            float ps[4] = {0.f, 0.f, 0.f, 0.f};
            #pragma unroll
            for (int nf = 0; nf < 4; ++nf) {
                #pragma unroll
                for (int r = 0; r < 4; ++r) {
                    float p = __expf(s[nf][r] - m[r]);
                    ps[r] += p;
                    int rowl = wr + g * 4 + r;
                    Pf[rowl][(nf * 16 + c) ^ ((rowl & 7) << 3)] = f16bits(p);
                }
            }
            #pragma unroll
            for (int r = 0; r < 4; ++r) {
                ps[r] += __shfl_xor(ps[r], 1, 64);
                ps[r] += __shfl_xor(ps[r], 2, 64);
                ps[r] += __shfl_xor(ps[r], 4, 64);
                ps[r] += __shfl_xor(ps[r], 8, 64);
                l[r] = l[r] * fct[r] + ps[r];
            }
            #pragma unroll
            for (int nf = 0; nf < 4; ++nf)
                #pragma unroll
                for (int r = 0; r < 4; ++r)
                    o[nf][r] *= fct[r];

            f16x8 pa[2];
            {
                int prow = wr + c;
                pa[0] = *(const f16x8*)&Pf[prow][(g * 8) ^ ((prow & 7) << 3)];
                pa[1] = *(const f16x8*)&Pf[prow][(32 + g * 8) ^ ((prow & 7) << 3)];
            }

            #pragma unroll
            for (int ss = 0; ss < 2; ++ss) {
                #pragma unroll
                for (int nf = 0; nf < 4; ++nf) {
                    int d = nf * 16 + c;
                    int kx = (ss * 32 + g * 8) ^ ((d & 7) << 3);
                    f16x8 vf = *(const f16x8*)&Vf[buf][d][kx];
                    o[nf] = __builtin_amdgcn_mfma_f32_16x16x32_f16(pa[ss], vf, o[nf], 0, 0, 0);
                }
            }
        }

        if (pre) vwrite(buf ^ 1, vr);
        __syncthreads();
        buf ^= 1;
    }

    unsigned short* pob = po + (size_t)slot * 4096;
    #pragma unroll
    for (int r = 0; r < 4; ++r) {
        int rowl = wr + g * 4 + r;
        if (!is_pano && rowl >= NS_) continue;
        #pragma unroll
        for (int nf = 0; nf < 4; ++nf)
            pob[rowl * 64 + nf * 16 + c] = f16bits(o[nf][r]);
        if (c == 0) {
            pm[(size_t)slot * 64 + rowl] = m[r];
            pl[(size_t)slot * 64 + rowl] = l[r];
        }
    }
}

// ---------------------------------------------------------------------------
// Fused combine -> fp16 att. Blocks [0,336) pano, [336,396) spatial.
// ---------------------------------------------------------------------------
__global__ __launch_bounds__(256)
void attn_comb(const unsigned short* __restrict__ po, const float* __restrict__ pm,
               const float* __restrict__ pl, unsigned short* __restrict__ attf)
{
    const int b = blockIdx.x;
    const int tid = threadIdx.x;
    if (b < 336) {
        const int pt = b % PTILES;
        const int t2 = b / PTILES;
        const int vw = t2 & 3;
        const int h  = t2 >> 2;
        const int d = tid & 63;
        const int rg = tid >> 6;
        const int tb = b * 3;

        for (int i = 0; i < 16; ++i) {
            int row = rg * 16 + i;
            int prow = pt * 64 + row;
            if (prow >= P_) break;
            float m0 = pm[(size_t)tb * 64 + row],       l0 = pl[(size_t)tb * 64 + row];
            float m1 = pm[(size_t)(tb + 1) * 64 + row], l1 = pl[(size_t)(tb + 1) * 64 + row];
            float m2 = pm[(size_t)(tb + 2) * 64 + row], l2 = pl[(size_t)(tb + 2) * 64 + row];
            float M = fmaxf(fmaxf(m0, m1), m2);
            float w0 = __expf(m0 - M), w1 = __expf(m1 - M), w2 = __expf(m2 - M);
            float inv = 1.0f / (l0 * w0 + l1 * w1 + l2 * w2);
            float o0 = f16val(po[(size_t)tb * 4096 + row * 64 + d]);
            float o1 = f16val(po[(size_t)(tb + 1) * 4096 + row * 64 + d]);
            float o2 = f16val(po[(size_t)(tb + 2) * 4096 + row * 64 + d]);
            float oo = (o0 * w0 + o1 * w1 + o2 * w2) * inv;
            size_t idx = ((size_t)(NS_ + vw * P_ + prow)) * C_ + h * 64 + d;
            attf[idx] = f16bits(oo);
        }
    } else {
        const int rid = (b - 336) * 4 + (tid >> 6);   // 0..239
        const int s = rid % NS_;
        const int h = rid / NS_;
        const int d = tid & 63;

        float M = -INFINITY;
        #pragma unroll 2
        for (int sp = 0; sp < SPL; ++sp)
            M = fmaxf(M, pm[(size_t)(NPANO + h * SPL + sp) * 64 + s]);
        float num = 0.f, den = 0.f;
        for (int sp = 0; sp < SPL; ++sp) {
            size_t sl = NPANO + h * SPL + sp;
            float w = __expf(pm[sl * 64 + s] - M);
            den = fmaf(pl[sl * 64 + s], w, den);
            num = fmaf(f16val(po[sl * 4096 + s * 64 + d]), w, num);
        }
        size_t idx = (size_t)s * C_ + h * 64 + d;
        attf[idx] = f16bits(num / den);
    }
}

// ---------------------------------------------------------------------------
extern "C" void kernel_launch(void* const* d_in, const int* in_sizes, int n_in,
                              void* d_out, int out_size, void* d_ws, size_t ws_size,
                              hipStream_t stream)
{
    const float* x       = (const float*)d_in[0];
    const float* qkv_w   = (const float*)d_in[1];
    const float* qkv_b   = (const float*)d_in[2];
    const float* proj_w  = (const float*)d_in[3];
    const float* proj_b  = (const float*)d_in[4];
    float* out = (float*)d_out;

    const size_t per = (size_t)H_ * N_ * D_;
    unsigned short* qph = (unsigned short*)d_ws;
    unsigned short* kph = qph + per;
    unsigned short* vph = kph + per;
    unsigned short* xf  = vph + per;
    unsigned short* wf  = xf + (size_t)N_ * C_;
    unsigned short* pwf = wf + (size_t)3 * C_ * C_;
    unsigned short* attf = pwf + (size_t)C_ * C_;
    unsigned short* ppo = attf + (size_t)N_ * C_;
    float* ppm = (float*)(ppo + (size_t)NPART * 4096);
    float* ppl = ppm + (size_t)NPART * 64;

    // 0) convert inputs to fp16
    {
        int total = N4_X + N4_W + N4_PW;
        cvt_all<<<(total + 255) / 256, 256, 0, stream>>>(x, qkv_w, proj_w, xf, wf, pwf);
    }

    // 1) QKV projection (fp16 MFMA, 3-buffer counted-vmcnt pipeline)
    gemm_f16<1><<<26 * 36, 256, 0, stream>>>(xf, wf, qkv_b, N_, 3 * C_,
                                             (float*)qph, (float*)kph, (float*)vph);

    // 2) unified attention partials
    attn_fused<<<NPART, 256, 0, stream>>>(qph, kph, vph, ppo, ppm, ppl);

    // 3) fused combine -> fp16 att
    attn_comb<<<396, 256, 0, stream>>>(ppo, ppm, ppl, attf);

    // 4) output projection
    gemm_f16<0><<<26 * 12, 256, 0, stream>>>(attf, pwf, proj_b, N_, C_, out, nullptr, nullptr);
}

// Round 18
// 72.502 us; speedup vs baseline: 1.0010x; 1.0010x over previous
//
#include <hip/hip_runtime.h>
#include <hip/hip_bf16.h>
#include <math.h>

#define H_  12
#define N_  1620
#define D_  64
#define C_  768
#define NS_ 20
#define V_  4
#define P_  400

#define TPP    64
#define PTILES 7    // ceil(400/64)
#define SPL    26   // spatial key splits of 64
#define NPANO  1008 // pano partial blocks: 336 tiles x 3 thirds
#define NPART  (NPANO + SPL * H_)   // 1320 total partial slots

typedef _Float16 f16x8 __attribute__((ext_vector_type(8)));
typedef float f32x4 __attribute__((ext_vector_type(4)));
typedef unsigned short ushort4v __attribute__((ext_vector_type(4)));
typedef unsigned int uint4v __attribute__((ext_vector_type(4)));

__device__ __forceinline__ unsigned short f16bits(float v) {
    return __builtin_bit_cast(unsigned short, (_Float16)v);
}
__device__ __forceinline__ float f16val(unsigned short u) {
    return (float)__builtin_bit_cast(_Float16, u);
}
// bijective XCD-chunked swizzle (m204)
__device__ __forceinline__ int xcd_swz(int orig, int nwg) {
    int q = nwg >> 3, r = nwg & 7;
    int x = orig & 7, p = orig >> 3;
    return (x < r ? x * (q + 1) : r * (q + 1) + (x - r) * q) + p;
}
__device__ __forceinline__ void gload16(const void* g, void* l) {
    __builtin_amdgcn_global_load_lds((const __attribute__((address_space(1))) void*)g,
                                     (__attribute__((address_space(3))) void*)l, 16, 0, 0);
}

// ---------------------------------------------------------------------------
#define N4_X  ((N_ * C_) / 4)
#define N4_W  ((3 * C_ * C_) / 4)
#define N4_PW ((C_ * C_) / 4)

__global__ __launch_bounds__(256)
void cvt_all(const float* __restrict__ x, const float* __restrict__ w,
             const float* __restrict__ pw,
             unsigned short* __restrict__ xf, unsigned short* __restrict__ wf,
             unsigned short* __restrict__ pwf)
{
    int i = blockIdx.x * 256 + threadIdx.x;
    const float* src; unsigned short* dst; int idx;
    if (i < N4_X)                { src = x;  dst = xf;  idx = i; }
    else if (i < N4_X + N4_W)    { src = w;  dst = wf;  idx = i - N4_X; }
    else if (i < N4_X + N4_W + N4_PW) { src = pw; dst = pwf; idx = i - N4_X - N4_W; }
    else return;
    float4 v = ((const float4*)src)[idx];
    ushort4v o;
    o.x = f16bits(v.x); o.y = f16bits(v.y); o.z = f16bits(v.z); o.w = f16bits(v.w);
    ((ushort4v*)dst)[idx] = o;
}

// ---------------------------------------------------------------------------
// Single-fp16 MFMA NT GEMM. Tile 64x64, BK=64, 4 waves (2x2, each 32x32).
// 3-buffer, 2-deep prefetch with COUNTED vmcnt + raw s_barrier:
//   iter t: wait vmcnt(t's loads done); s_barrier; STAGE(t+2); COMPUTE(t).
// STAGE = 4 global_load_lds per wave, so in-flight at the wait is <=8 and
// vmcnt(4) leaves only t+1's loads pending. Stage(t+2) is safe after the
// barrier: all waves have finished COMPUTE(t-1), which used buffer (t+2)%3.
// ---------------------------------------------------------------------------
template<int MODE>
__global__ __launch_bounds__(256)
void gemm_f16(const unsigned short* __restrict__ A, const unsigned short* __restrict__ B,
              const float* __restrict__ bias, int M, int N,
              float* __restrict__ out0, float* __restrict__ out1, float* __restrict__ out2)
{
    __shared__ unsigned short Ash[3][64][64];
    __shared__ unsigned short Bsh[3][64][64];
    const int tid = threadIdx.x;
    const int lane = tid & 63;
    const int w = tid >> 6;
    const int c = lane & 15;
    const int g = lane >> 4;

    const int wg = xcd_swz(blockIdx.x, gridDim.x);
    const int tmc = (M + 63) >> 6;
    const int tm = (wg % tmc) * 64;
    const int tn = (wg / tmc) * 64;

    const int wm = (w >> 1) * 32;
    const int wn = (w & 1) * 32;

    f32x4 acc[2][2] = {};

    const int srow = lane >> 3;
    const int ksrc = (((lane & 7) ^ srow) << 3);
    int gmA = tm + w * 16 + srow;
    const int gnB = tn + w * 16 + srow;

    auto STAGE = [&](int buf, int k0) {
        #pragma unroll
        for (int t = 0; t < 2; ++t) {
            int gm = gmA + t * 8; if (gm > M - 1) gm = M - 1;
            gload16(A + (size_t)gm * 768 + k0 + ksrc, &Ash[buf][w * 16 + t * 8][0]);
            gload16(B + (size_t)(gnB + t * 8) * 768 + k0 + ksrc, &Bsh[buf][w * 16 + t * 8][0]);
        }
    };
    auto COMPUTE = [&](int buf) {
        #pragma unroll
        for (int ss = 0; ss < 2; ++ss) {
            f16x8 af[2], bf[2];
            #pragma unroll
            for (int i = 0; i < 2; ++i) {
                int ra = wm + i * 16 + c;
                af[i] = *(const f16x8*)&Ash[buf][ra][(ss * 32 + g * 8) ^ ((ra & 7) << 3)];
                int rb = wn + i * 16 + c;
                bf[i] = *(const f16x8*)&Bsh[buf][rb][(ss * 32 + g * 8) ^ ((rb & 7) << 3)];
            }
            #pragma unroll
            for (int mi = 0; mi < 2; ++mi)
                #pragma unroll
                for (int ni = 0; ni < 2; ++ni)
                    acc[mi][ni] = __builtin_amdgcn_mfma_f32_16x16x32_f16(af[mi], bf[ni], acc[mi][ni], 0, 0, 0);
        }
    };

    // prologue: 2 tiles in flight
    STAGE(0, 0);
    STAGE(1, 64);
    for (int t = 0; t < 12; ++t) {
        if (t < 11) asm volatile("s_waitcnt vmcnt(4)" ::: "memory");
        else        asm volatile("s_waitcnt vmcnt(0)" ::: "memory");
        __builtin_amdgcn_s_barrier();
        if (t + 2 < 12) STAGE((t + 2) % 3, (t + 2) * 64);
        COMPUTE(t % 3);
    }

    const int fq = g * 4;
    #pragma unroll
    for (int mi = 0; mi < 2; ++mi) {
        #pragma unroll
        for (int ni = 0; ni < 2; ++ni) {
            int n = tn + wn + ni * 16 + c;
            float bb = bias[n];
            #pragma unroll
            for (int r = 0; r < 4; ++r) {
                int m = tm + wm + mi * 16 + fq + r;
                if (m >= M) continue;
                float val = acc[mi][ni][r] + bb;
                if (MODE == 0) {
                    out0[(size_t)m * N + n] = val;
                } else {
                    int which = n / C_;
                    int rr = n - which * C_;
                    int h = rr >> 6, d = rr & 63;
                    float* dst = (which == 0) ? out0 : (which == 1) ? out1 : out2;
                    ((unsigned short*)dst)[((size_t)h * N_ + m) * D_ + d] = f16bits(val);
                }
            }
        }
    }
}

// ---------------------------------------------------------------------------
// Unified attention partials, single-fp16 MFMA flash, double-buffered chunks.
// LDS 40 KB, one __syncthreads per chunk. Spatial blocks predicate waves with
// no live rows (wr >= 20) off the compute path (they still stage + barrier).
// ---------------------------------------------------------------------------
__global__ __launch_bounds__(256)
void attn_fused(const unsigned short* __restrict__ qp, const unsigned short* __restrict__ kp,
                const unsigned short* __restrict__ vp,
                unsigned short* __restrict__ po, float* __restrict__ pm, float* __restrict__ pl)
{
    __shared__ unsigned short Kf[2][64][64];
    __shared__ unsigned short Vf[2][64][64];
    __shared__ unsigned short Pf[64][64];

    const int tid = threadIdx.x;
    const int lane = tid & 63;
    const int w = tid >> 6;
    const int wr = w * 16;
    const int c = lane & 15;
    const int g = lane >> 4;

    const bool is_pano = (blockIdx.x < NPANO);
    int h, vw = 0, p0 = 0, cv = 0, n0 = 0, ch_lo, ch_hi, slot;
    if (is_pano) {
        int wg = xcd_swz(blockIdx.x, NPANO);
        int third = wg % 3;
        int t = wg / 3;
        int pt = t % PTILES;
        int t2 = t / PTILES;
        vw = t2 & 3;
        h  = t2 >> 2;
        p0 = pt * TPP;
        cv = (vw + 1) & 3;
        ch_lo = third * 3;
        ch_hi = third * 3 + 3;
        slot = wg;
    } else {
        int id = blockIdx.x - NPANO;
        int sp = id % SPL;
        h = id / SPL;
        n0 = sp * 64;
        ch_lo = 0; ch_hi = 1;
        slot = NPANO + id;
    }
    const bool active = is_pano || (wr < NS_);   // wave-uniform

    auto keyrow = [&](int ch, int key) -> int {
        int n;
        if (!is_pano) {
            n = n0 + key; if (n > N_ - 1) n = N_ - 1;
        } else if (ch < 7) {
            int sj = ch * 64 + key;
            n = (sj < NS_) ? sj : (NS_ + vw * P_ + (sj - NS_));
            if (sj >= NS_ + P_) n = 0;
        } else {
            int pp = p0 + (ch - 7) * 64 + key;
            if (pp >= P_) pp -= P_;
            if (pp >= P_) pp -= P_;
            n = NS_ + cv * P_ + pp;
        }
        return n;
    };

    auto stage_k = [&](int buf, int ch) {
        #pragma unroll
        for (int t = 0; t < 2; ++t) {
            int key = wr + t * 8 + (lane >> 3);
            int n = keyrow(ch, key);
            int dsrc = ((lane & 7) ^ (key & 7)) << 3;
            gload16(kp + (((size_t)h * N_ + n) << 6) + dsrc, &Kf[buf][wr + t * 8][0]);
        }
    };
    auto vload = [&](ushort4v* rr, int ch) {
        int kg = (tid & 15) << 2;
        int dq = (tid >> 4) << 2;
        #pragma unroll
        for (int tt = 0; tt < 4; ++tt) {
            int n = keyrow(ch, kg + tt);
            rr[tt] = *(const ushort4v*)(vp + (((size_t)h * N_ + n) << 6) + dq);
        }
    };
    auto vwrite = [&](int buf, const ushort4v* rr) {
        int kg = (tid & 15) << 2;
        int dq = (tid >> 4) << 2;
        #pragma unroll
        for (int j = 0; j < 4; ++j) {
            int d = dq + j;
            ushort4v wv;
            wv.x = rr[0][j]; wv.y = rr[1][j]; wv.z = rr[2][j]; wv.w = rr[3][j];
            *(ushort4v*)&Vf[buf][d][kg ^ ((d & 7) << 3)] = wv;
        }
    };

    f16x8 qf[2];
    {
        int rowq;
        if (is_pano) { rowq = NS_ + vw * P_ + p0 + wr + c; if (rowq > N_ - 1) rowq = N_ - 1; }
        else         { rowq = wr + c; if (rowq > NS_ - 1) rowq = NS_ - 1; }
        const unsigned short* qrow = qp + (((size_t)h * N_ + rowq) << 6);
        qf[0] = *(const f16x8*)(qrow + g * 8);
        qf[1] = *(const f16x8*)(qrow + 32 + g * 8);
    }

    float m[4], l[4];
    f32x4 o[4] = {};
    #pragma unroll
    for (int r = 0; r < 4; ++r) { m[r] = -INFINITY; l[r] = 0.f; }

    ushort4v vr[4];
    stage_k(0, ch_lo);
    vload(vr, ch_lo);
    vwrite(0, vr);
    __syncthreads();

    int buf = 0;
    for (int ch = ch_lo; ch < ch_hi; ++ch) {
        const bool pre = (ch + 1 < ch_hi);
        if (pre) {
            stage_k(buf ^ 1, ch + 1);
            vload(vr, ch + 1);
        }

        if (active) {
            f32x4 s[4] = {};
            #pragma unroll
            for (int ss = 0; ss < 2; ++ss) {
                #pragma unroll
                for (int nf = 0; nf < 4; ++nf) {
                    int key = nf * 16 + c;
                    int dx = (ss * 32 + g * 8) ^ ((key & 7) << 3);
                    f16x8 kf = *(const f16x8*)&Kf[buf][key][dx];
                    s[nf] = __builtin_amdgcn_mfma_f32_16x16x32_f16(qf[ss], kf, s[nf], 0, 0, 0);
                }
            }

            #pragma unroll
            for (int nf = 0; nf < 4; ++nf) {
                int col = nf * 16 + c;
                #pragma unroll
                for (int r = 0; r < 4; ++r) {
                    int rowl = wr + g * 4 + r;
                    bool valid;
                    if (!is_pano) {
                        valid = (n0 + col) < N_;
                    } else if (ch < 7) {
                        valid = (ch * 64 + col) < (NS_ + P_);
                    } else {
                        int i = (ch - 7) * 64 + col;
                        valid = (i < 127) && ((unsigned)(i - rowl) < 64u);
                    }
                    s[nf][r] = valid ? s[nf][r] * 0.125f : -INFINITY;
                }
            }

            float fct[4];
            #pragma unroll
            for (int r = 0; r < 4; ++r) {
                float cm = fmaxf(fmaxf(s[0][r], s[1][r]), fmaxf(s[2][r], s[3][r]));
                cm = fmaxf(cm, __shfl_xor(cm, 1, 64));
                cm = fmaxf(cm, __shfl_xor(cm, 2, 64));
                cm = fmaxf(cm, __shfl_xor(cm, 4, 64));
                cm = fmaxf(cm, __shfl_xor(cm, 8, 64));
                float nm = fmaxf(m[r], cm);
                fct[r] = __expf(m[r] - nm);
                m[r] = nm;
            }

            float ps[4] = {0.f, 0.f, 0.f, 0.f};
            #pragma unroll
            for (int nf = 0; nf < 4; ++nf) {
                #pragma unroll
                for (int r = 0; r < 4; ++r) {
                    float p = __expf(s[nf][r] - m[r]);
                    ps[r] += p;
                    int rowl = wr + g * 4 + r;
                    Pf[rowl][(nf * 16 + c) ^ ((rowl & 7) << 3)] = f16bits(p);
                }
            }
            #pragma unroll
            for (int r = 0; r < 4; ++r) {
                ps[r] += __shfl_xor(ps[r], 1, 64);
                ps[r] += __shfl_xor(ps[r], 2, 64);
                ps[r] += __shfl_xor(ps[r], 4, 64);
                ps[r] += __shfl_xor(ps[r], 8, 64);
                l[r] = l[r] * fct[r] + ps[r];
            }
            #pragma unroll
            for (int nf = 0; nf < 4; ++nf)
                #pragma unroll
                for (int r = 0; r < 4; ++r)
                    o[nf][r] *= fct[r];

            f16x8 pa[2];
            {
                int prow = wr + c;
                pa[0] = *(const f16x8*)&Pf[prow][(g * 8) ^ ((prow & 7) << 3)];
                pa[1] = *(const f16x8*)&Pf[prow][(32 + g * 8) ^ ((prow & 7) << 3)];
            }

            #pragma unroll
            for (int ss = 0; ss < 2; ++ss) {
                #pragma unroll
                for (int nf = 0; nf < 4; ++nf) {
                    int d = nf * 16 + c;
                    int kx = (ss * 32 + g * 8) ^ ((d & 7) << 3);
                    f16x8 vf = *(const f16x8*)&Vf[buf][d][kx];
                    o[nf] = __builtin_amdgcn_mfma_f32_16x16x32_f16(pa[ss], vf, o[nf], 0, 0, 0);
                }
            }
        }

        if (pre) vwrite(buf ^ 1, vr);
        __syncthreads();
        buf ^= 1;
    }

    unsigned short* pob = po + (size_t)slot * 4096;
    #pragma unroll
    for (int r = 0; r < 4; ++r) {
        int rowl = wr + g * 4 + r;
        if (!is_pano && rowl >= NS_) continue;
        #pragma unroll
        for (int nf = 0; nf < 4; ++nf)
            pob[rowl * 64 + nf * 16 + c] = f16bits(o[nf][r]);
        if (c == 0) {
            pm[(size_t)slot * 64 + rowl] = m[r];
            pl[(size_t)slot * 64 + rowl] = l[r];
        }
    }
}

// ---------------------------------------------------------------------------
// Fused combine -> fp16 att. Blocks [0,336) pano, [336,396) spatial.
// ---------------------------------------------------------------------------
__global__ __launch_bounds__(256)
void attn_comb(const unsigned short* __restrict__ po, const float* __restrict__ pm,
               const float* __restrict__ pl, unsigned short* __restrict__ attf)
{
    const int b = blockIdx.x;
    const int tid = threadIdx.x;
    if (b < 336) {
        const int pt = b % PTILES;
        const int t2 = b / PTILES;
        const int vw = t2 & 3;
        const int h  = t2 >> 2;
        const int d = tid & 63;
        const int rg = tid >> 6;
        const int tb = b * 3;

        for (int i = 0; i < 16; ++i) {
            int row = rg * 16 + i;
            int prow = pt * 64 + row;
            if (prow >= P_) break;
            float m0 = pm[(size_t)tb * 64 + row],       l0 = pl[(size_t)tb * 64 + row];
            float m1 = pm[(size_t)(tb + 1) * 64 + row], l1 = pl[(size_t)(tb + 1) * 64 + row];
            float m2 = pm[(size_t)(tb + 2) * 64 + row], l2 = pl[(size_t)(tb + 2) * 64 + row];
            float M = fmaxf(fmaxf(m0, m1), m2);
            float w0 = __expf(m0 - M), w1 = __expf(m1 - M), w2 = __expf(m2 - M);
            float inv = 1.0f / (l0 * w0 + l1 * w1 + l2 * w2);
            float o0 = f16val(po[(size_t)tb * 4096 + row * 64 + d]);
            float o1 = f16val(po[(size_t)(tb + 1) * 4096 + row * 64 + d]);
            float o2 = f16val(po[(size_t)(tb + 2) * 4096 + row * 64 + d]);
            float oo = (o0 * w0 + o1 * w1 + o2 * w2) * inv;
            size_t idx = ((size_t)(NS_ + vw * P_ + prow)) * C_ + h * 64 + d;
            attf[idx] = f16bits(oo);
        }
    } else {
        const int rid = (b - 336) * 4 + (tid >> 6);   // 0..239
        const int s = rid % NS_;
        const int h = rid / NS_;
        const int d = tid & 63;

        float M = -INFINITY;
        #pragma unroll 2
        for (int sp = 0; sp < SPL; ++sp)
            M = fmaxf(M, pm[(size_t)(NPANO + h * SPL + sp) * 64 + s]);
        float num = 0.f, den = 0.f;
        for (int sp = 0; sp < SPL; ++sp) {
            size_t sl = NPANO + h * SPL + sp;
            float w = __expf(pm[sl * 64 + s] - M);
            den = fmaf(pl[sl * 64 + s], w, den);
            num = fmaf(f16val(po[sl * 4096 + s * 64 + d]), w, num);
        }
        size_t idx = (size_t)s * C_ + h * 64 + d;
        attf[idx] = f16bits(num / den);
    }
}

// ---------------------------------------------------------------------------
extern "C" void kernel_launch(void* const* d_in, const int* in_sizes, int n_in,
                              void* d_out, int out_size, void* d_ws, size_t ws_size,
                              hipStream_t stream)
{
    const float* x       = (const float*)d_in[0];
    const float* qkv_w   = (const float*)d_in[1];
    const float* qkv_b   = (const float*)d_in[2];
    const float* proj_w  = (const float*)d_in[3];
    const float* proj_b  = (const float*)d_in[4];
    float* out = (float*)d_out;

    const size_t per = (size_t)H_ * N_ * D_;
    unsigned short* qph = (unsigned short*)d_ws;
    unsigned short* kph = qph + per;
    unsigned short* vph = kph + per;
    unsigned short* xf  = vph + per;
    unsigned short* wf  = xf + (size_t)N_ * C_;
    unsigned short* pwf = wf + (size_t)3 * C_ * C_;
    unsigned short* attf = pwf + (size_t)C_ * C_;
    unsigned short* ppo = attf + (size_t)N_ * C_;
    float* ppm = (float*)(ppo + (size_t)NPART * 4096);
    float* ppl = ppm + (size_t)NPART * 64;

    // 0) convert inputs to fp16
    {
        int total = N4_X + N4_W + N4_PW;
        cvt_all<<<(total + 255) / 256, 256, 0, stream>>>(x, qkv_w, proj_w, xf, wf, pwf);
    }

    // 1) QKV projection (fp16 MFMA, 3-buffer counted-vmcnt pipeline)
    gemm_f16<1><<<26 * 36, 256, 0, stream>>>(xf, wf, qkv_b, N_, 3 * C_,
                                             (float*)qph, (float*)kph, (float*)vph);

    // 2) unified attention partials
    attn_fused<<<NPART, 256, 0, stream>>>(qph, kph, vph, ppo, ppm, ppl);

    // 3) fused combine -> fp16 att
    attn_comb<<<396, 256, 0, stream>>>(ppo, ppm, ppl, attf);

    // 4) output projection
    gemm_f16<0><<<26 * 12, 256, 0, stream>>>(attf, pwf, proj_b, N_, C_, out, nullptr, nullptr);
}

// Round 19
// 67.897 us; speedup vs baseline: 1.0689x; 1.0678x over previous
//
#include <hip/hip_runtime.h>
#include <hip/hip_bf16.h>
#include <math.h>

#define H_  12
#define N_  1620
#define D_  64
#define C_  768
#define NS_ 20
#define V_  4
#define P_  400

#define TPP    64
#define PTILES 7    // ceil(400/64)
#define SPL    26   // spatial key splits of 64
#define NPANO  1008 // pano partial blocks: 336 tiles x 3 thirds
#define NPART  (NPANO + SPL * H_)   // 1320 total partial slots

typedef _Float16 f16x8 __attribute__((ext_vector_type(8)));
typedef float f32x4 __attribute__((ext_vector_type(4)));
typedef unsigned short ushort4v __attribute__((ext_vector_type(4)));
typedef unsigned int uint4v __attribute__((ext_vector_type(4)));

__device__ __forceinline__ unsigned short f16bits(float v) {
    return __builtin_bit_cast(unsigned short, (_Float16)v);
}
__device__ __forceinline__ float f16val(unsigned short u) {
    return (float)__builtin_bit_cast(_Float16, u);
}
// bijective XCD-chunked swizzle (m204)
__device__ __forceinline__ int xcd_swz(int orig, int nwg) {
    int q = nwg >> 3, r = nwg & 7;
    int x = orig & 7, p = orig >> 3;
    return (x < r ? x * (q + 1) : r * (q + 1) + (x - r) * q) + p;
}
__device__ __forceinline__ void gload16(const void* g, void* l) {
    __builtin_amdgcn_global_load_lds((const __attribute__((address_space(1))) void*)g,
                                     (__attribute__((address_space(3))) void*)l, 16, 0, 0);
}

// ---------------------------------------------------------------------------
#define N4_X  ((N_ * C_) / 4)
#define N4_W  ((3 * C_ * C_) / 4)
#define N4_PW ((C_ * C_) / 4)

__global__ __launch_bounds__(256)
void cvt_all(const float* __restrict__ x, const float* __restrict__ w,
             const float* __restrict__ pw,
             unsigned short* __restrict__ xf, unsigned short* __restrict__ wf,
             unsigned short* __restrict__ pwf)
{
    int i = blockIdx.x * 256 + threadIdx.x;
    const float* src; unsigned short* dst; int idx;
    if (i < N4_X)                { src = x;  dst = xf;  idx = i; }
    else if (i < N4_X + N4_W)    { src = w;  dst = wf;  idx = i - N4_X; }
    else if (i < N4_X + N4_W + N4_PW) { src = pw; dst = pwf; idx = i - N4_X - N4_W; }
    else return;
    float4 v = ((const float4*)src)[idx];
    ushort4v o;
    o.x = f16bits(v.x); o.y = f16bits(v.y); o.z = f16bits(v.z); o.w = f16bits(v.w);
    ((ushort4v*)dst)[idx] = o;
}

// ---------------------------------------------------------------------------
// Single-fp16 MFMA NT GEMM. Tile 64x64, BK=64, 4 waves (2x2, each 32x32),
// 2-buffer double-buffered (r15 proven form); staging via pre-swizzled
// global_load_lds (linear dest, XOR'd global k-block); reads same XOR.
// MODE 0: f32 out. MODE 1: QKV scatter; writes fp16 q/k/v [h][N_][D_].
// ---------------------------------------------------------------------------
template<int MODE>
__global__ __launch_bounds__(256)
void gemm_f16(const unsigned short* __restrict__ A, const unsigned short* __restrict__ B,
              const float* __restrict__ bias, int M, int N,
              float* __restrict__ out0, float* __restrict__ out1, float* __restrict__ out2)
{
    __shared__ unsigned short Ash[2][64][64];
    __shared__ unsigned short Bsh[2][64][64];
    const int tid = threadIdx.x;
    const int lane = tid & 63;
    const int w = tid >> 6;
    const int c = lane & 15;
    const int g = lane >> 4;

    const int wg = xcd_swz(blockIdx.x, gridDim.x);
    const int tmc = (M + 63) >> 6;
    const int tm = (wg % tmc) * 64;
    const int tn = (wg / tmc) * 64;

    const int wm = (w >> 1) * 32;
    const int wn = (w & 1) * 32;

    f32x4 acc[2][2] = {};

    const int srow = lane >> 3;
    const int ksrc = (((lane & 7) ^ srow) << 3);
    int gmA = tm + w * 16 + srow;
    const int gnB = tn + w * 16 + srow;

    auto STAGE = [&](int buf, int k0) {
        #pragma unroll
        for (int t = 0; t < 2; ++t) {
            int gm = gmA + t * 8; if (gm > M - 1) gm = M - 1;
            gload16(A + (size_t)gm * 768 + k0 + ksrc, &Ash[buf][w * 16 + t * 8][0]);
            gload16(B + (size_t)(gnB + t * 8) * 768 + k0 + ksrc, &Bsh[buf][w * 16 + t * 8][0]);
        }
    };
    auto COMPUTE = [&](int buf) {
        #pragma unroll
        for (int ss = 0; ss < 2; ++ss) {
            f16x8 af[2], bf[2];
            #pragma unroll
            for (int i = 0; i < 2; ++i) {
                int ra = wm + i * 16 + c;
                af[i] = *(const f16x8*)&Ash[buf][ra][(ss * 32 + g * 8) ^ ((ra & 7) << 3)];
                int rb = wn + i * 16 + c;
                bf[i] = *(const f16x8*)&Bsh[buf][rb][(ss * 32 + g * 8) ^ ((rb & 7) << 3)];
            }
            #pragma unroll
            for (int mi = 0; mi < 2; ++mi)
                #pragma unroll
                for (int ni = 0; ni < 2; ++ni)
                    acc[mi][ni] = __builtin_amdgcn_mfma_f32_16x16x32_f16(af[mi], bf[ni], acc[mi][ni], 0, 0, 0);
        }
    };

    STAGE(0, 0);
    __syncthreads();
    int cur = 0;
    for (int t = 0; t < 11; ++t) {
        STAGE(cur ^ 1, (t + 1) * 64);
        COMPUTE(cur);
        __syncthreads();
        cur ^= 1;
    }
    COMPUTE(cur);

    const int fq = g * 4;
    #pragma unroll
    for (int mi = 0; mi < 2; ++mi) {
        #pragma unroll
        for (int ni = 0; ni < 2; ++ni) {
            int n = tn + wn + ni * 16 + c;
            float bb = bias[n];
            #pragma unroll
            for (int r = 0; r < 4; ++r) {
                int m = tm + wm + mi * 16 + fq + r;
                if (m >= M) continue;
                float val = acc[mi][ni][r] + bb;
                if (MODE == 0) {
                    out0[(size_t)m * N + n] = val;
                } else {
                    int which = n / C_;
                    int rr = n - which * C_;
                    int h = rr >> 6, d = rr & 63;
                    float* dst = (which == 0) ? out0 : (which == 1) ? out1 : out2;
                    ((unsigned short*)dst)[((size_t)h * N_ + m) * D_ + d] = f16bits(val);
                }
            }
        }
    }
}

// ---------------------------------------------------------------------------
// Unified attention partials, single-fp16 MFMA flash, double-buffered chunks.
// LDS 40 KB, one __syncthreads per chunk. Spatial blocks predicate waves with
// no live rows (wr >= 20) off the compute path (they still stage + barrier).
// ---------------------------------------------------------------------------
__global__ __launch_bounds__(256)
void attn_fused(const unsigned short* __restrict__ qp, const unsigned short* __restrict__ kp,
                const unsigned short* __restrict__ vp,
                unsigned short* __restrict__ po, float* __restrict__ pm, float* __restrict__ pl)
{
    __shared__ unsigned short Kf[2][64][64];
    __shared__ unsigned short Vf[2][64][64];
    __shared__ unsigned short Pf[64][64];

    const int tid = threadIdx.x;
    const int lane = tid & 63;
    const int w = tid >> 6;
    const int wr = w * 16;
    const int c = lane & 15;
    const int g = lane >> 4;

    const bool is_pano = (blockIdx.x < NPANO);
    int h, vw = 0, p0 = 0, cv = 0, n0 = 0, ch_lo, ch_hi, slot;
    if (is_pano) {
        int wg = xcd_swz(blockIdx.x, NPANO);
        int third = wg % 3;
        int t = wg / 3;
        int pt = t % PTILES;
        int t2 = t / PTILES;
        vw = t2 & 3;
        h  = t2 >> 2;
        p0 = pt * TPP;
        cv = (vw + 1) & 3;
        ch_lo = third * 3;
        ch_hi = third * 3 + 3;
        slot = wg;
    } else {
        int id = blockIdx.x - NPANO;
        int sp = id % SPL;
        h = id / SPL;
        n0 = sp * 64;
        ch_lo = 0; ch_hi = 1;
        slot = NPANO + id;
    }
    const bool active = is_pano || (wr < NS_);   // wave-uniform

    auto keyrow = [&](int ch, int key) -> int {
        int n;
        if (!is_pano) {
            n = n0 + key; if (n > N_ - 1) n = N_ - 1;
        } else if (ch < 7) {
            int sj = ch * 64 + key;
            n = (sj < NS_) ? sj : (NS_ + vw * P_ + (sj - NS_));
            if (sj >= NS_ + P_) n = 0;
        } else {
            int pp = p0 + (ch - 7) * 64 + key;
            if (pp >= P_) pp -= P_;
            if (pp >= P_) pp -= P_;
            n = NS_ + cv * P_ + pp;
        }
        return n;
    };

    auto stage_k = [&](int buf, int ch) {
        #pragma unroll
        for (int t = 0; t < 2; ++t) {
            int key = wr + t * 8 + (lane >> 3);
            int n = keyrow(ch, key);
            int dsrc = ((lane & 7) ^ (key & 7)) << 3;
            gload16(kp + (((size_t)h * N_ + n) << 6) + dsrc, &Kf[buf][wr + t * 8][0]);
        }
    };
    auto vload = [&](ushort4v* rr, int ch) {
        int kg = (tid & 15) << 2;
        int dq = (tid >> 4) << 2;
        #pragma unroll
        for (int tt = 0; tt < 4; ++tt) {
            int n = keyrow(ch, kg + tt);
            rr[tt] = *(const ushort4v*)(vp + (((size_t)h * N_ + n) << 6) + dq);
        }
    };
    auto vwrite = [&](int buf, const ushort4v* rr) {
        int kg = (tid & 15) << 2;
        int dq = (tid >> 4) << 2;
        #pragma unroll
        for (int j = 0; j < 4; ++j) {
            int d = dq + j;
            ushort4v wv;
            wv.x = rr[0][j]; wv.y = rr[1][j]; wv.z = rr[2][j]; wv.w = rr[3][j];
            *(ushort4v*)&Vf[buf][d][kg ^ ((d & 7) << 3)] = wv;
        }
    };

    f16x8 qf[2];
    {
        int rowq;
        if (is_pano) { rowq = NS_ + vw * P_ + p0 + wr + c; if (rowq > N_ - 1) rowq = N_ - 1; }
        else         { rowq = wr + c; if (rowq > NS_ - 1) rowq = NS_ - 1; }
        const unsigned short* qrow = qp + (((size_t)h * N_ + rowq) << 6);
        qf[0] = *(const f16x8*)(qrow + g * 8);
        qf[1] = *(const f16x8*)(qrow + 32 + g * 8);
    }

    float m[4], l[4];
    f32x4 o[4] = {};
    #pragma unroll
    for (int r = 0; r < 4; ++r) { m[r] = -INFINITY; l[r] = 0.f; }

    ushort4v vr[4];
    stage_k(0, ch_lo);
    vload(vr, ch_lo);
    vwrite(0, vr);
    __syncthreads();

    int buf = 0;
    for (int ch = ch_lo; ch < ch_hi; ++ch) {
        const bool pre = (ch + 1 < ch_hi);
        if (pre) {
            stage_k(buf ^ 1, ch + 1);
            vload(vr, ch + 1);
        }

        if (active) {
            f32x4 s[4] = {};
            #pragma unroll
            for (int ss = 0; ss < 2; ++ss) {
                #pragma unroll
                for (int nf = 0; nf < 4; ++nf) {
                    int key = nf * 16 + c;
                    int dx = (ss * 32 + g * 8) ^ ((key & 7) << 3);
                    f16x8 kf = *(const f16x8*)&Kf[buf][key][dx];
                    s[nf] = __builtin_amdgcn_mfma_f32_16x16x32_f16(qf[ss], kf, s[nf], 0, 0, 0);
                }
            }

            #pragma unroll
            for (int nf = 0; nf < 4; ++nf) {
                int col = nf * 16 + c;
                #pragma unroll
                for (int r = 0; r < 4; ++r) {
                    int rowl = wr + g * 4 + r;
                    bool valid;
                    if (!is_pano) {
                        valid = (n0 + col) < N_;
                    } else if (ch < 7) {
                        valid = (ch * 64 + col) < (NS_ + P_);
                    } else {
                        int i = (ch - 7) * 64 + col;
                        valid = (i < 127) && ((unsigned)(i - rowl) < 64u);
                    }
                    s[nf][r] = valid ? s[nf][r] * 0.125f : -INFINITY;
                }
            }

            float fct[4];
            #pragma unroll
            for (int r = 0; r < 4; ++r) {
                float cm = fmaxf(fmaxf(s[0][r], s[1][r]), fmaxf(s[2][r], s[3][r]));
                cm = fmaxf(cm, __shfl_xor(cm, 1, 64));
                cm = fmaxf(cm, __shfl_xor(cm, 2, 64));
                cm = fmaxf(cm, __shfl_xor(cm, 4, 64));
                cm = fmaxf(cm, __shfl_xor(cm, 8, 64));
                float nm = fmaxf(m[r], cm);
                fct[r] = __expf(m[r] - nm);
                m[r] = nm;
            }

            float ps[4] = {0.f, 0.f, 0.f, 0.f};
            #pragma unroll
            for (int nf = 0; nf < 4; ++nf) {
                #pragma unroll
                for (int r = 0; r < 4; ++r) {
                    float p = __expf(s[nf][r] - m[r]);
                    ps[r] += p;
                    int rowl = wr + g * 4 + r;
                    Pf[rowl][(nf * 16 + c) ^ ((rowl & 7) << 3)] = f16bits(p);
                }
            }
            #pragma unroll
            for (int r = 0; r < 4; ++r) {
                ps[r] += __shfl_xor(ps[r], 1, 64);
                ps[r] += __shfl_xor(ps[r], 2, 64);
                ps[r] += __shfl_xor(ps[r], 4, 64);
                ps[r] += __shfl_xor(ps[r], 8, 64);
                l[r] = l[r] * fct[r] + ps[r];
            }
            #pragma unroll
            for (int nf = 0; nf < 4; ++nf)
                #pragma unroll
                for (int r = 0; r < 4; ++r)
                    o[nf][r] *= fct[r];

            f16x8 pa[2];
            {
                int prow = wr + c;
                pa[0] = *(const f16x8*)&Pf[prow][(g * 8) ^ ((prow & 7) << 3)];
                pa[1] = *(const f16x8*)&Pf[prow][(32 + g * 8) ^ ((prow & 7) << 3)];
            }

            #pragma unroll
            for (int ss = 0; ss < 2; ++ss) {
                #pragma unroll
                for (int nf = 0; nf < 4; ++nf) {
                    int d = nf * 16 + c;
                    int kx = (ss * 32 + g * 8) ^ ((d & 7) << 3);
                    f16x8 vf = *(const f16x8*)&Vf[buf][d][kx];
                    o[nf] = __builtin_amdgcn_mfma_f32_16x16x32_f16(pa[ss], vf, o[nf], 0, 0, 0);
                }
            }
        }

        if (pre) vwrite(buf ^ 1, vr);
        __syncthreads();
        buf ^= 1;
    }

    unsigned short* pob = po + (size_t)slot * 4096;
    #pragma unroll
    for (int r = 0; r < 4; ++r) {
        int rowl = wr + g * 4 + r;
        if (!is_pano && rowl >= NS_) continue;
        #pragma unroll
        for (int nf = 0; nf < 4; ++nf)
            pob[rowl * 64 + nf * 16 + c] = f16bits(o[nf][r]);
        if (c == 0) {
            pm[(size_t)slot * 64 + rowl] = m[r];
            pl[(size_t)slot * 64 + rowl] = l[r];
        }
    }
}

// ---------------------------------------------------------------------------
// Fused combine -> fp16 att. Blocks [0,336) pano, [336,396) spatial.
// ---------------------------------------------------------------------------
__global__ __launch_bounds__(256)
void attn_comb(const unsigned short* __restrict__ po, const float* __restrict__ pm,
               const float* __restrict__ pl, unsigned short* __restrict__ attf)
{
    const int b = blockIdx.x;
    const int tid = threadIdx.x;
    if (b < 336) {
        const int pt = b % PTILES;
        const int t2 = b / PTILES;
        const int vw = t2 & 3;
        const int h  = t2 >> 2;
        const int d = tid & 63;
        const int rg = tid >> 6;
        const int tb = b * 3;

        for (int i = 0; i < 16; ++i) {
            int row = rg * 16 + i;
            int prow = pt * 64 + row;
            if (prow >= P_) break;
            float m0 = pm[(size_t)tb * 64 + row],       l0 = pl[(size_t)tb * 64 + row];
            float m1 = pm[(size_t)(tb + 1) * 64 + row], l1 = pl[(size_t)(tb + 1) * 64 + row];
            float m2 = pm[(size_t)(tb + 2) * 64 + row], l2 = pl[(size_t)(tb + 2) * 64 + row];
            float M = fmaxf(fmaxf(m0, m1), m2);
            float w0 = __expf(m0 - M), w1 = __expf(m1 - M), w2 = __expf(m2 - M);
            float inv = 1.0f / (l0 * w0 + l1 * w1 + l2 * w2);
            float o0 = f16val(po[(size_t)tb * 4096 + row * 64 + d]);
            float o1 = f16val(po[(size_t)(tb + 1) * 4096 + row * 64 + d]);
            float o2 = f16val(po[(size_t)(tb + 2) * 4096 + row * 64 + d]);
            float oo = (o0 * w0 + o1 * w1 + o2 * w2) * inv;
            size_t idx = ((size_t)(NS_ + vw * P_ + prow)) * C_ + h * 64 + d;
            attf[idx] = f16bits(oo);
        }
    } else {
        const int rid = (b - 336) * 4 + (tid >> 6);   // 0..239
        const int s = rid % NS_;
        const int h = rid / NS_;
        const int d = tid & 63;

        float M = -INFINITY;
        #pragma unroll 2
        for (int sp = 0; sp < SPL; ++sp)
            M = fmaxf(M, pm[(size_t)(NPANO + h * SPL + sp) * 64 + s]);
        float num = 0.f, den = 0.f;
        for (int sp = 0; sp < SPL; ++sp) {
            size_t sl = NPANO + h * SPL + sp;
            float w = __expf(pm[sl * 64 + s] - M);
            den = fmaf(pl[sl * 64 + s], w, den);
            num = fmaf(f16val(po[sl * 4096 + s * 64 + d]), w, num);
        }
        size_t idx = (size_t)s * C_ + h * 64 + d;
        attf[idx] = f16bits(num / den);
    }
}

// ---------------------------------------------------------------------------
extern "C" void kernel_launch(void* const* d_in, const int* in_sizes, int n_in,
                              void* d_out, int out_size, void* d_ws, size_t ws_size,
                              hipStream_t stream)
{
    const float* x       = (const float*)d_in[0];
    const float* qkv_w   = (const float*)d_in[1];
    const float* qkv_b   = (const float*)d_in[2];
    const float* proj_w  = (const float*)d_in[3];
    const float* proj_b  = (const float*)d_in[4];
    float* out = (float*)d_out;

    const size_t per = (size_t)H_ * N_ * D_;
    unsigned short* qph = (unsigned short*)d_ws;
    unsigned short* kph = qph + per;
    unsigned short* vph = kph + per;
    unsigned short* xf  = vph + per;
    unsigned short* wf  = xf + (size_t)N_ * C_;
    unsigned short* pwf = wf + (size_t)3 * C_ * C_;
    unsigned short* attf = pwf + (size_t)C_ * C_;
    unsigned short* ppo = attf + (size_t)N_ * C_;
    float* ppm = (float*)(ppo + (size_t)NPART * 4096);
    float* ppl = ppm + (size_t)NPART * 64;

    // 0) convert inputs to fp16
    {
        int total = N4_X + N4_W + N4_PW;
        cvt_all<<<(total + 255) / 256, 256, 0, stream>>>(x, qkv_w, proj_w, xf, wf, pwf);
    }

    // 1) QKV projection (fp16 MFMA, 2-buffer double-buffered)
    gemm_f16<1><<<26 * 36, 256, 0, stream>>>(xf, wf, qkv_b, N_, 3 * C_,
                                             (float*)qph, (float*)kph, (float*)vph);

    // 2) unified attention partials
    attn_fused<<<NPART, 256, 0, stream>>>(qph, kph, vph, ppo, ppm, ppl);

    // 3) fused combine -> fp16 att
    attn_comb<<<396, 256, 0, stream>>>(ppo, ppm, ppl, attf);

    // 4) output projection
    gemm_f16<0><<<26 * 12, 256, 0, stream>>>(attf, pwf, proj_b, N_, C_, out, nullptr, nullptr);
}

// Round 20
// 63.080 us; speedup vs baseline: 1.1506x; 1.0764x over previous
//
#include <hip/hip_runtime.h>
#include <hip/hip_bf16.h>
#include <math.h>

#define H_  12
#define N_  1620
#define D_  64
#define C_  768
#define NS_ 20
#define V_  4
#define P_  400

#define TPP    64
#define PTILES 7    // ceil(400/64)
#define SPL    26   // spatial key splits of 64
#define NPANO  1008 // pano partial blocks: 336 tiles x 3 thirds
#define NPART  (NPANO + SPL * H_)   // 1320 total partial slots

typedef _Float16 f16x8 __attribute__((ext_vector_type(8)));
typedef float f32x4 __attribute__((ext_vector_type(4)));
typedef unsigned short ushort4v __attribute__((ext_vector_type(4)));
typedef unsigned int uint4v __attribute__((ext_vector_type(4)));

__device__ __forceinline__ unsigned short f16bits(float v) {
    return __builtin_bit_cast(unsigned short, (_Float16)v);
}
__device__ __forceinline__ float f16val(unsigned short u) {
    return (float)__builtin_bit_cast(_Float16, u);
}
// bijective XCD-chunked swizzle (m204)
__device__ __forceinline__ int xcd_swz(int orig, int nwg) {
    int q = nwg >> 3, r = nwg & 7;
    int x = orig & 7, p = orig >> 3;
    return (x < r ? x * (q + 1) : r * (q + 1) + (x - r) * q) + p;
}
__device__ __forceinline__ void gload16(const void* g, void* l) {
    __builtin_amdgcn_global_load_lds((const __attribute__((address_space(1))) void*)g,
                                     (__attribute__((address_space(3))) void*)l, 16, 0, 0);
}

// ---------------------------------------------------------------------------
#define N4_X  ((N_ * C_) / 4)
#define N4_W  ((3 * C_ * C_) / 4)
#define N4_PW ((C_ * C_) / 4)

__global__ __launch_bounds__(256)
void cvt_all(const float* __restrict__ x, const float* __restrict__ w,
             const float* __restrict__ pw,
             unsigned short* __restrict__ xf, unsigned short* __restrict__ wf,
             unsigned short* __restrict__ pwf)
{
    int i = blockIdx.x * 256 + threadIdx.x;
    const float* src; unsigned short* dst; int idx;
    if (i < N4_X)                { src = x;  dst = xf;  idx = i; }
    else if (i < N4_X + N4_W)    { src = w;  dst = wf;  idx = i - N4_X; }
    else if (i < N4_X + N4_W + N4_PW) { src = pw; dst = pwf; idx = i - N4_X - N4_W; }
    else return;
    float4 v = ((const float4*)src)[idx];
    ushort4v o;
    o.x = f16bits(v.x); o.y = f16bits(v.y); o.z = f16bits(v.z); o.w = f16bits(v.w);
    ((ushort4v*)dst)[idx] = o;
}

// ---------------------------------------------------------------------------
// Single-fp16 MFMA NT GEMM. Tile 64x64, BK=64, 4 waves (2x2, each 32x32),
// 2-buffer double-buffered (proven r15 form).
// ---------------------------------------------------------------------------
template<int MODE>
__global__ __launch_bounds__(256)
void gemm_f16(const unsigned short* __restrict__ A, const unsigned short* __restrict__ B,
              const float* __restrict__ bias, int M, int N,
              float* __restrict__ out0, float* __restrict__ out1, float* __restrict__ out2)
{
    __shared__ unsigned short Ash[2][64][64];
    __shared__ unsigned short Bsh[2][64][64];
    const int tid = threadIdx.x;
    const int lane = tid & 63;
    const int w = tid >> 6;
    const int c = lane & 15;
    const int g = lane >> 4;

    const int wg = xcd_swz(blockIdx.x, gridDim.x);
    const int tmc = (M + 63) >> 6;
    const int tm = (wg % tmc) * 64;
    const int tn = (wg / tmc) * 64;

    const int wm = (w >> 1) * 32;
    const int wn = (w & 1) * 32;

    f32x4 acc[2][2] = {};

    const int srow = lane >> 3;
    const int ksrc = (((lane & 7) ^ srow) << 3);
    int gmA = tm + w * 16 + srow;
    const int gnB = tn + w * 16 + srow;

    auto STAGE = [&](int buf, int k0) {
        #pragma unroll
        for (int t = 0; t < 2; ++t) {
            int gm = gmA + t * 8; if (gm > M - 1) gm = M - 1;
            gload16(A + (size_t)gm * 768 + k0 + ksrc, &Ash[buf][w * 16 + t * 8][0]);
            gload16(B + (size_t)(gnB + t * 8) * 768 + k0 + ksrc, &Bsh[buf][w * 16 + t * 8][0]);
        }
    };
    auto COMPUTE = [&](int buf) {
        #pragma unroll
        for (int ss = 0; ss < 2; ++ss) {
            f16x8 af[2], bf[2];
            #pragma unroll
            for (int i = 0; i < 2; ++i) {
                int ra = wm + i * 16 + c;
                af[i] = *(const f16x8*)&Ash[buf][ra][(ss * 32 + g * 8) ^ ((ra & 7) << 3)];
                int rb = wn + i * 16 + c;
                bf[i] = *(const f16x8*)&Bsh[buf][rb][(ss * 32 + g * 8) ^ ((rb & 7) << 3)];
            }
            #pragma unroll
            for (int mi = 0; mi < 2; ++mi)
                #pragma unroll
                for (int ni = 0; ni < 2; ++ni)
                    acc[mi][ni] = __builtin_amdgcn_mfma_f32_16x16x32_f16(af[mi], bf[ni], acc[mi][ni], 0, 0, 0);
        }
    };

    STAGE(0, 0);
    __syncthreads();
    int cur = 0;
    for (int t = 0; t < 11; ++t) {
        STAGE(cur ^ 1, (t + 1) * 64);
        COMPUTE(cur);
        __syncthreads();
        cur ^= 1;
    }
    COMPUTE(cur);

    const int fq = g * 4;
    #pragma unroll
    for (int mi = 0; mi < 2; ++mi) {
        #pragma unroll
        for (int ni = 0; ni < 2; ++ni) {
            int n = tn + wn + ni * 16 + c;
            float bb = bias[n];
            #pragma unroll
            for (int r = 0; r < 4; ++r) {
                int m = tm + wm + mi * 16 + fq + r;
                if (m >= M) continue;
                float val = acc[mi][ni][r] + bb;
                if (MODE == 0) {
                    out0[(size_t)m * N + n] = val;
                } else {
                    int which = n / C_;
                    int rr = n - which * C_;
                    int h = rr >> 6, d = rr & 63;
                    float* dst = (which == 0) ? out0 : (which == 1) ? out1 : out2;
                    ((unsigned short*)dst)[((size_t)h * N_ + m) * D_ + d] = f16bits(val);
                }
            }
        }
    }
}

// ---------------------------------------------------------------------------
// Unified attention partials, fp16 MFMA flash with SWAPPED QK^T:
// s = mfma(K_frag, Q_frag) so each thread owns 16 keys of ONE query row
// (qrow = wr + c). Softmax row-reduce = 15 per-thread ops + 2 shfl_xor;
// m/l are per-thread scalars; P-writes pack 4 keys -> ds_write_b64.
// LDS 40 KB, 1 barrier/chunk, double-buffered K/V.
// ---------------------------------------------------------------------------
__global__ __launch_bounds__(256)
void attn_fused(const unsigned short* __restrict__ qp, const unsigned short* __restrict__ kp,
                const unsigned short* __restrict__ vp,
                unsigned short* __restrict__ po, float* __restrict__ pm, float* __restrict__ pl)
{
    __shared__ unsigned short Kf[2][64][64];
    __shared__ unsigned short Vf[2][64][64];
    __shared__ unsigned short Pf[64][64];

    const int tid = threadIdx.x;
    const int lane = tid & 63;
    const int w = tid >> 6;
    const int wr = w * 16;
    const int c = lane & 15;
    const int g = lane >> 4;
    const int qrl = wr + c;             // this thread's query row (local)

    const bool is_pano = (blockIdx.x < NPANO);
    int h, vw = 0, p0 = 0, cv = 0, n0 = 0, ch_lo, ch_hi, slot;
    if (is_pano) {
        int wg = xcd_swz(blockIdx.x, NPANO);
        int third = wg % 3;
        int t = wg / 3;
        int pt = t % PTILES;
        int t2 = t / PTILES;
        vw = t2 & 3;
        h  = t2 >> 2;
        p0 = pt * TPP;
        cv = (vw + 1) & 3;
        ch_lo = third * 3;
        ch_hi = third * 3 + 3;
        slot = wg;
    } else {
        int id = blockIdx.x - NPANO;
        int sp = id % SPL;
        h = id / SPL;
        n0 = sp * 64;
        ch_lo = 0; ch_hi = 1;
        slot = NPANO + id;
    }
    const bool active = is_pano || (wr < NS_);   // wave-uniform

    auto keyrow = [&](int ch, int key) -> int {
        int n;
        if (!is_pano) {
            n = n0 + key; if (n > N_ - 1) n = N_ - 1;
        } else if (ch < 7) {
            int sj = ch * 64 + key;
            n = (sj < NS_) ? sj : (NS_ + vw * P_ + (sj - NS_));
            if (sj >= NS_ + P_) n = 0;
        } else {
            int pp = p0 + (ch - 7) * 64 + key;
            if (pp >= P_) pp -= P_;
            if (pp >= P_) pp -= P_;
            n = NS_ + cv * P_ + pp;
        }
        return n;
    };

    auto stage_k = [&](int buf, int ch) {
        #pragma unroll
        for (int t = 0; t < 2; ++t) {
            int key = wr + t * 8 + (lane >> 3);
            int n = keyrow(ch, key);
            int dsrc = ((lane & 7) ^ (key & 7)) << 3;
            gload16(kp + (((size_t)h * N_ + n) << 6) + dsrc, &Kf[buf][wr + t * 8][0]);
        }
    };
    auto vload = [&](ushort4v* rr, int ch) {
        int kg = (tid & 15) << 2;
        int dq = (tid >> 4) << 2;
        #pragma unroll
        for (int tt = 0; tt < 4; ++tt) {
            int n = keyrow(ch, kg + tt);
            rr[tt] = *(const ushort4v*)(vp + (((size_t)h * N_ + n) << 6) + dq);
        }
    };
    auto vwrite = [&](int buf, const ushort4v* rr) {
        int kg = (tid & 15) << 2;
        int dq = (tid >> 4) << 2;
        #pragma unroll
        for (int j = 0; j < 4; ++j) {
            int d = dq + j;
            ushort4v wv;
            wv.x = rr[0][j]; wv.y = rr[1][j]; wv.z = rr[2][j]; wv.w = rr[3][j];
            *(ushort4v*)&Vf[buf][d][kg ^ ((d & 7) << 3)] = wv;
        }
    };

    f16x8 qf[2];
    {
        int rowq;
        if (is_pano) { rowq = NS_ + vw * P_ + p0 + qrl; if (rowq > N_ - 1) rowq = N_ - 1; }
        else         { rowq = qrl; if (rowq > NS_ - 1) rowq = NS_ - 1; }
        const unsigned short* qrow = qp + (((size_t)h * N_ + rowq) << 6);
        qf[0] = *(const f16x8*)(qrow + g * 8);
        qf[1] = *(const f16x8*)(qrow + 32 + g * 8);
    }

    float m_own = -INFINITY, l_own = 0.f;   // state for qrow qrl
    f32x4 o[4] = {};                        // rows wr+g*4+r, cols d=nf*16+c

    ushort4v vr[4];
    stage_k(0, ch_lo);
    vload(vr, ch_lo);
    vwrite(0, vr);
    __syncthreads();

    int buf = 0;
    for (int ch = ch_lo; ch < ch_hi; ++ch) {
        const bool pre = (ch + 1 < ch_hi);
        if (pre) {
            stage_k(buf ^ 1, ch + 1);
            vload(vr, ch + 1);
        }

        if (active) {
            // ---- S^T = K x Q^T : s[nf][r] = S[key=nf*16+g*4+r][qrow=qrl] ----
            f32x4 s[4] = {};
            #pragma unroll
            for (int ss = 0; ss < 2; ++ss) {
                #pragma unroll
                for (int nf = 0; nf < 4; ++nf) {
                    int key = nf * 16 + c;
                    int dx = (ss * 32 + g * 8) ^ ((key & 7) << 3);
                    f16x8 kf = *(const f16x8*)&Kf[buf][key][dx];
                    s[nf] = __builtin_amdgcn_mfma_f32_16x16x32_f16(kf, qf[ss], s[nf], 0, 0, 0);
                }
            }

            // ---- mask + scale (key = nf*16+g*4+r, qrow = qrl) ----
            #pragma unroll
            for (int nf = 0; nf < 4; ++nf) {
                #pragma unroll
                for (int r = 0; r < 4; ++r) {
                    int key = nf * 16 + g * 4 + r;
                    bool valid;
                    if (!is_pano) {
                        valid = (n0 + key) < N_;
                    } else if (ch < 7) {
                        valid = (ch * 64 + key) < (NS_ + P_);
                    } else {
                        int i = (ch - 7) * 64 + key;
                        valid = (i < 127) && ((unsigned)(i - qrl) < 64u);
                    }
                    s[nf][r] = valid ? s[nf][r] * 0.125f : -INFINITY;
                }
            }

            // ---- softmax: per-thread over 16 keys + 2 shfl across g ----
            float cm = s[0][0];
            #pragma unroll
            for (int nf = 0; nf < 4; ++nf)
                #pragma unroll
                for (int r = 0; r < 4; ++r)
                    cm = fmaxf(cm, s[nf][r]);
            cm = fmaxf(cm, __shfl_xor(cm, 16, 64));
            cm = fmaxf(cm, __shfl_xor(cm, 32, 64));
            float nm = fmaxf(m_own, cm);
            float fct = __expf(m_own - nm);
            m_own = nm;

            float ps = 0.f;
            #pragma unroll
            for (int nf = 0; nf < 4; ++nf) {
                float pe[4];
                #pragma unroll
                for (int r = 0; r < 4; ++r) {
                    pe[r] = __expf(s[nf][r] - m_own);
                    ps += pe[r];
                }
                ushort4v p4;
                p4.x = f16bits(pe[0]); p4.y = f16bits(pe[1]);
                p4.z = f16bits(pe[2]); p4.w = f16bits(pe[3]);
                *(ushort4v*)&Pf[qrl][(nf * 16 + g * 4) ^ ((qrl & 7) << 3)] = p4;
            }
            ps += __shfl_xor(ps, 16, 64);
            ps += __shfl_xor(ps, 32, 64);
            l_own = l_own * fct + ps;

            // ---- rescale o with per-row factors (broadcast from c-lanes) ----
            float fr[4];
            #pragma unroll
            for (int r = 0; r < 4; ++r) fr[r] = __shfl(fct, g * 4 + r, 64);
            #pragma unroll
            for (int nf = 0; nf < 4; ++nf)
                #pragma unroll
                for (int r = 0; r < 4; ++r)
                    o[nf][r] *= fr[r];

            // ---- P A-frags (row qrl written by this wave's c-lanes) ----
            f16x8 pa[2];
            pa[0] = *(const f16x8*)&Pf[qrl][(g * 8) ^ ((qrl & 7) << 3)];
            pa[1] = *(const f16x8*)&Pf[qrl][(32 + g * 8) ^ ((qrl & 7) << 3)];

            // ---- PV ----
            #pragma unroll
            for (int ss = 0; ss < 2; ++ss) {
                #pragma unroll
                for (int nf = 0; nf < 4; ++nf) {
                    int d = nf * 16 + c;
                    int kx = (ss * 32 + g * 8) ^ ((d & 7) << 3);
                    f16x8 vf = *(const f16x8*)&Vf[buf][d][kx];
                    o[nf] = __builtin_amdgcn_mfma_f32_16x16x32_f16(pa[ss], vf, o[nf], 0, 0, 0);
                }
            }
        }

        if (pre) vwrite(buf ^ 1, vr);
        __syncthreads();
        buf ^= 1;
    }

    // ---- write partials (m/l broadcast to row layout) ----
    unsigned short* pob = po + (size_t)slot * 4096;
    #pragma unroll
    for (int r = 0; r < 4; ++r) {
        int rowl = wr + g * 4 + r;
        if (!is_pano && rowl >= NS_) continue;
        #pragma unroll
        for (int nf = 0; nf < 4; ++nf)
            pob[rowl * 64 + nf * 16 + c] = f16bits(o[nf][r]);
        float mr = __shfl(m_own, g * 4 + r, 64);
        float lr = __shfl(l_own, g * 4 + r, 64);
        if (c == 0) {
            pm[(size_t)slot * 64 + rowl] = mr;
            pl[(size_t)slot * 64 + rowl] = lr;
        }
    }
}

// ---------------------------------------------------------------------------
// Fused combine -> fp16 att. Blocks [0,336) pano, [336,396) spatial.
// ---------------------------------------------------------------------------
__global__ __launch_bounds__(256)
void attn_comb(const unsigned short* __restrict__ po, const float* __restrict__ pm,
               const float* __restrict__ pl, unsigned short* __restrict__ attf)
{
    const int b = blockIdx.x;
    const int tid = threadIdx.x;
    if (b < 336) {
        const int pt = b % PTILES;
        const int t2 = b / PTILES;
        const int vw = t2 & 3;
        const int h  = t2 >> 2;
        const int d = tid & 63;
        const int rg = tid >> 6;
        const int tb = b * 3;

        for (int i = 0; i < 16; ++i) {
            int row = rg * 16 + i;
            int prow = pt * 64 + row;
            if (prow >= P_) break;
            float m0 = pm[(size_t)tb * 64 + row],       l0 = pl[(size_t)tb * 64 + row];
            float m1 = pm[(size_t)(tb + 1) * 64 + row], l1 = pl[(size_t)(tb + 1) * 64 + row];
            float m2 = pm[(size_t)(tb + 2) * 64 + row], l2 = pl[(size_t)(tb + 2) * 64 + row];
            float M = fmaxf(fmaxf(m0, m1), m2);
            float w0 = __expf(m0 - M), w1 = __expf(m1 - M), w2 = __expf(m2 - M);
            float inv = 1.0f / (l0 * w0 + l1 * w1 + l2 * w2);
            float o0 = f16val(po[(size_t)tb * 4096 + row * 64 + d]);
            float o1 = f16val(po[(size_t)(tb + 1) * 4096 + row * 64 + d]);
            float o2 = f16val(po[(size_t)(tb + 2) * 4096 + row * 64 + d]);
            float oo = (o0 * w0 + o1 * w1 + o2 * w2) * inv;
            size_t idx = ((size_t)(NS_ + vw * P_ + prow)) * C_ + h * 64 + d;
            attf[idx] = f16bits(oo);
        }
    } else {
        const int rid = (b - 336) * 4 + (tid >> 6);   // 0..239
        const int s = rid % NS_;
        const int h = rid / NS_;
        const int d = tid & 63;

        float M = -INFINITY;
        #pragma unroll 2
        for (int sp = 0; sp < SPL; ++sp)
            M = fmaxf(M, pm[(size_t)(NPANO + h * SPL + sp) * 64 + s]);
        float num = 0.f, den = 0.f;
        for (int sp = 0; sp < SPL; ++sp) {
            size_t sl = NPANO + h * SPL + sp;
            float w = __expf(pm[sl * 64 + s] - M);
            den = fmaf(pl[sl * 64 + s], w, den);
            num = fmaf(f16val(po[sl * 4096 + s * 64 + d]), w, num);
        }
        size_t idx = (size_t)s * C_ + h * 64 + d;
        attf[idx] = f16bits(num / den);
    }
}

// ---------------------------------------------------------------------------
extern "C" void kernel_launch(void* const* d_in, const int* in_sizes, int n_in,
                              void* d_out, int out_size, void* d_ws, size_t ws_size,
                              hipStream_t stream)
{
    const float* x       = (const float*)d_in[0];
    const float* qkv_w   = (const float*)d_in[1];
    const float* qkv_b   = (const float*)d_in[2];
    const float* proj_w  = (const float*)d_in[3];
    const float* proj_b  = (const float*)d_in[4];
    float* out = (float*)d_out;

    const size_t per = (size_t)H_ * N_ * D_;
    unsigned short* qph = (unsigned short*)d_ws;
    unsigned short* kph = qph + per;
    unsigned short* vph = kph + per;
    unsigned short* xf  = vph + per;
    unsigned short* wf  = xf + (size_t)N_ * C_;
    unsigned short* pwf = wf + (size_t)3 * C_ * C_;
    unsigned short* attf = pwf + (size_t)C_ * C_;
    unsigned short* ppo = attf + (size_t)N_ * C_;
    float* ppm = (float*)(ppo + (size_t)NPART * 4096);
    float* ppl = ppm + (size_t)NPART * 64;

    // 0) convert inputs to fp16
    {
        int total = N4_X + N4_W + N4_PW;
        cvt_all<<<(total + 255) / 256, 256, 0, stream>>>(x, qkv_w, proj_w, xf, wf, pwf);
    }

    // 1) QKV projection (fp16 MFMA, 2-buffer double-buffered)
    gemm_f16<1><<<26 * 36, 256, 0, stream>>>(xf, wf, qkv_b, N_, 3 * C_,
                                             (float*)qph, (float*)kph, (float*)vph);

    // 2) unified attention partials (swapped-QK^T fp16 MFMA)
    attn_fused<<<NPART, 256, 0, stream>>>(qph, kph, vph, ppo, ppm, ppl);

    // 3) fused combine -> fp16 att
    attn_comb<<<396, 256, 0, stream>>>(ppo, ppm, ppl, attf);

    // 4) output projection
    gemm_f16<0><<<26 * 12, 256, 0, stream>>>(attf, pwf, proj_b, N_, C_, out, nullptr, nullptr);
}